// Round 10
// baseline (392.912 us; speedup 1.0000x reference)
//
#include <hip/hip_runtime.h>
#include <stdint.h>
#include <stddef.h>

// ---------------------------------------------------------------------------
// BayesianDTW forward on MI355X — R16: margin/overhead trims on R15.
// Base: R15 (passed, 302us, absmax 8.0; 4 cols/lane, SW=256, 4 stripes).
// Three changes, all protocol/addressing (no math changes):
//  1. CH 8 -> 4: lag per hop 96 -> 80 steps (publish f=m-16; consumer needs
//     flag m+4 => producer 20 boundaries x 4 steps). Makespan 863 -> 815.
//  2. lane_shr1: DPP ROW_BCAST15 (0x142) replaces the 3 readlane->cndmask
//     patches (lanes 16/32/48 <- 15/31/47) with 1 DPP + 1 cndmask — removes
//     SGPR round-trips from the carried chain.
//  3. XCD co-location: remap bid -> (b,s) so the 4 stripes of a batch share
//     bid mod 8 (same XCD under round-robin dispatch): x=bid&7, g=bid>>3,
//     s=g&3, b=(g>>2)*8+x; upstream = bid-8. All flag/edge coherent traffic
//     becomes intra-XCD (L2-local) instead of cross-XCD.
// Everything else R15-verbatim: 4-cell lse3 chain (R3-proven), W scatter
// reg-ring depth 4, estage compact edge buffer w/ ws_size guard + out-column
// fallback, hidden fpoll, vmcnt-counted publish, 3-deep edge prefetch.
// vmcnt proofs at CH=4: between boundaries 4 W loads + edge_st => vmcnt(4)
// leaves {edge_st_m, 3 W loads} => edge_st_{m-1} drained -> publish f=m-16.
// Final block: vmcnt(1) -> publish 127; vmcnt(0) -> publish 128.
// ---------------------------------------------------------------------------

#define NBATCH  32
#define NA      512
#define NB      1024
#define NSTRIPE 4
#define SW      256          // cols per stripe (4 per lane)
#define CH      4            // rows per chunk (R16: was 8)
#define NCHUNK  (NA / CH)    // 128
#define LSTR    260          // lds_o row stride (floats; 256 + 4 pad)
#define OROWS   513
#define OCOLS   1025
#define FSTRIDE 32           // flag padding: 128 B
#define NBID    (NBATCH * NSTRIPE)
// edge staging: floats, [bid][chunk][4] contiguous (16B per chunk)
#define ESTAGE_OFF_U32 (NBID * FSTRIDE)              // after flags (16KB)
#define WS_NEEDED ((size_t)((NBID * FSTRIDE + NBID * NCHUNK * 4) * 4))

#define NEGV    (-1e20f)
#define LOG2E   (1.4426950408889634f)
#define LN2     (0.6931471805599453f)
#define NEG2    (-1.4426950408889634e20f)   // NEGV in log2 units
#define FLAGTAG 0x5A000000u

#define EXP2F(x) __builtin_amdgcn_exp2f(x)   // v_exp_f32: 2^x
#define LOG2F(x) __builtin_amdgcn_logf(x)    // v_log_f32: log2(x)

__device__ __forceinline__ float lse3_2(float a, float b, float c) {
    // log2(2^a + 2^b + 2^c), log2 units. exp2 of the max is exactly 1 ->
    // only 2 transcendentals. NaN-free for finite inputs (diffs <= 0).
    float m  = fmaxf(fmaxf(a, b), c);                  // v_max3_f32
    float md = __builtin_amdgcn_fmed3f(a, b, c);       // v_med3_f32
    float mn = fminf(fminf(a, b), c);                  // v_min3_f32
    float ss = 1.0f + EXP2F(md - m) + EXP2F(mn - m);
    return m + LOG2F(ss);
}

__device__ __forceinline__ float rdlane(float v, int l) {
    return __int_as_float(__builtin_amdgcn_readlane(__float_as_int(v), l));
}

// lane i <- lane i-1 across the full wave, pure VALU, no SGPR round-trip:
// DPP ROW_SHR:1 (0x111) within 16-lane rows; DPP ROW_BCAST15 (0x142) gives
// lanes 16..31 <- lane15, 32..47 <- lane31, 48..63 <- lane47. Select bcast
// at lanes 16/32/48 (lane 0's result unused — edge path).
__device__ __forceinline__ float lane_shr1(float x, bool patch16) {
    int xi  = __float_as_int(x);
    int shr = __builtin_amdgcn_update_dpp(0, xi, 0x111, 0xf, 0xf, true);
    int bc  = __builtin_amdgcn_update_dpp(0, xi, 0x142, 0xf, 0xf, true);
    return __int_as_float(patch16 ? bc : shr);
}

__device__ __forceinline__ unsigned int ld_flag(unsigned int* fp) {
    return __hip_atomic_load(fp, __ATOMIC_RELAXED, __HIP_MEMORY_SCOPE_AGENT);
}
__device__ __forceinline__ void st_flag(unsigned int* fp, unsigned int v) {
    __hip_atomic_store(fp, v, __ATOMIC_RELAXED, __HIP_MEMORY_SCOPE_AGENT);
}
__device__ __forceinline__ float ld_edge(const float* p) {
    return __hip_atomic_load((float*)p, __ATOMIC_RELAXED, __HIP_MEMORY_SCOPE_AGENT);
}
__device__ __forceinline__ void st_edge(float* p, float v) {
    __hip_atomic_store(p, v, __ATOMIC_RELAXED, __HIP_MEMORY_SCOPE_AGENT);
}

__device__ __forceinline__ void wait_flag(unsigned int* fp, unsigned int need) {
    for (int k = 0; k < (1 << 22); ++k) {
        unsigned int v = ld_flag(fp);
        if ((v >> 24) == 0x5Au && (v & 0x00FFFFFFu) >= need) break;
    }
    asm volatile("" ::: "memory");
}

__global__ __launch_bounds__(64, 1)
void dtw_pipe(const float* __restrict__ W, float* __restrict__ out,
              unsigned int* __restrict__ flags, int use_stage)
{
    extern __shared__ float lds_o[];   // 128 x LSTR output ring (ln units)

    const int lane = (int)threadIdx.x;
    const int bid  = (int)blockIdx.x;
    // XCD co-location remap: stripes of a batch share bid mod 8 (same XCD).
    const int x = bid & 7;
    const int g = bid >> 3;
    const int s = g & 3;
    const int b = ((g >> 2) << 3) + x;

    const float*  Wb  = W + ((size_t)b * NA) * NB + s * SW;
    float*        ob  = out + (size_t)b * OROWS * OCOLS;
    unsigned int* fmy = flags + (size_t)bid * FSTRIDE;
    unsigned int* fup = flags + (size_t)(bid - 8) * FSTRIDE;      // (b, s-1)
    float*        emy = (float*)(flags + ESTAGE_OFF_U32) + (size_t)bid * NCHUNK * 4;
    float*        eup = (float*)(flags + ESTAGE_OFF_U32) + (size_t)(bid - 8) * NCHUNK * 4;

    const bool patch16 = (lane == 16) | (lane == 32) | (lane == 48);

    // ---- boundary cells of output (final values; nobody reads these) ----
    #pragma unroll
    for (int k = 0; k < 4; ++k)
        ob[s * SW + 1 + 4 * lane + k] = NEGV;
    if (s == 0) {
        if (lane == 0) ob[0] = 0.0f;
        for (int r = lane; r < NA; r += 64)
            ob[(size_t)(r + 1) * OCOLS] = NEGV;
    }

    // ---- W register ring: prime rows 0..3 (clamped; r(t)=t-lane) ----
    float4 wr[4];
    #pragma unroll
    for (int k = 0; k < 4; ++k) {
        int rowc = k - lane;
        rowc = rowc < 0 ? 0 : rowc;
        wr[k] = *(const float4*)&Wb[(size_t)rowc * NB + 4 * lane];
    }

    // ---- edge prefetch (log2 units; lanes 0..3 hold 4 rows each) ----
    float evcur = -1e30f, evnxt = -1e30f, lres = -1e30f;
    if (s > 0) {
        wait_flag(fup, 1u);
        if (lane < CH)
            evcur = (use_stage ? ld_edge(&eup[0 * 4 + lane])
                               : ld_edge(&ob[(size_t)(1 + lane) * OCOLS + s * SW]))
                    * LOG2E;
        wait_flag(fup, 2u);
        if (lane < CH)
            evnxt = (use_stage ? ld_edge(&eup[1 * 4 + lane])
                               : ld_edge(&ob[(size_t)(CH + 1 + lane) * OCOLS + s * SW]))
                    * LOG2E;
        wait_flag(fup, 3u);
        if (lane < CH)
            lres  = (use_stage ? ld_edge(&eup[2 * 4 + lane])
                               : ld_edge(&ob[(size_t)(2 * CH + 1 + lane) * OCOLS + s * SW]))
                    * LOG2E;
    }

    asm volatile("s_waitcnt vmcnt(0)" ::: "memory");   // primes + edges done

    // ---- systolic state (log2 units, R3-proven, 4 cells/lane) ----
    float top0 = NEG2, top1 = NEG2, top2 = NEG2, top3 = NEG2;
    float sh_in = NEG2;               // left neighbor's u3 from prev step
    float tl_reg = NEG2;              // mu[i-1, col0-1]
    float ev_im1 = (s == 0) ? 0.0f : NEG2;  // lane0 topleft
    unsigned int fpoll = 0;

    auto stepc = [&](int m, int tt, bool GATE, bool GNA) {
        const int t = 4 * m + tt;
        const int r = t - lane;
        if (tt == 1 && s > 0) fpoll = ld_flag(fup);      // hidden poll
        const float4 wv = wr[tt & 3];                    // copy, then refill
        {   // issue W load for row r+4 into the same slot
            int rowc = r + 4;
            rowc = rowc < 0 ? 0 : (rowc > NA - 1 ? NA - 1 : rowc);
            wr[tt & 3] = *(const float4*)&Wb[(size_t)rowc * NB + 4 * lane];
        }
        const float ev_i = rdlane(evcur, tt);
        // ---- carried chain: 4 serial cells (R3-proven algebra) ----
        const float lf = (lane == 0) ? ev_i   : sh_in;   // mu[i, col0-1]
        const float tl = (lane == 0) ? ev_im1 : tl_reg;  // mu[i-1, col0-1]
        const float u0 = fmaf(wv.x, LOG2E, lse3_2(top0, lf, tl));
        const float u1 = fmaf(wv.y, LOG2E, lse3_2(top1, u0, top0));
        const float u2 = fmaf(wv.z, LOG2E, lse3_2(top2, u1, top1));
        const float u3 = fmaf(wv.w, LOG2E, lse3_2(top3, u2, top2));
        bool db = true;
        if (GATE) db = (r >= 0);
        if (GNA)  db = (r < NA);
        if (db) {   // off-chain store (ln units), 16B aligned ds_write_b128
            *(float4*)&lds_o[(r & 127) * LSTR + 4 * lane]
                = make_float4(u0 * LN2, u1 * LN2, u2 * LN2, u3 * LN2);
        }
        if (GATE) {
            const bool on = (r >= 0);
            top0 = on ? u0 : NEG2;  top1 = on ? u1 : NEG2;
            top2 = on ? u2 : NEG2;  top3 = on ? u3 : NEG2;
            tl_reg = on ? lf : NEG2;
        } else {
            top0 = u0; top1 = u1; top2 = u2; top3 = u3; tl_reg = lf;
        }
        ev_im1 = ev_i;
        sh_in  = lane_shr1(u3, patch16);                 // pure-VALU pass
    };

    auto boundary = [&](int m) {
        const int f = m - 16;                 // chunk fully complete (skew 63)
        // 1) coherent edge publish for chunk f (staged: one 16B line;
        //    fallback: 4-line strided out-column dup).
        if (s < NSTRIPE - 1 && f >= 0 && lane < CH) {
            const int rw = (f << 2) + lane;
            const float evl = lds_o[(rw & 127) * LSTR + (SW - 1)];
            if (use_stage) st_edge(&emy[(size_t)f * 4 + lane], evl);
            else st_edge(ob + (size_t)(rw + 1) * OCOLS + (s + 1) * SW, evl);
        }
        // 2) vmcnt(4): between boundaries = 4 W loads; +this publish = 5.
        //    vmcnt(4) leaves {publish_m, 3 newest W loads} -> publish(f-1)
        //    from boundary m-1 drained -> flag v=f claims chunks <= f-1.
        asm volatile("s_waitcnt vmcnt(4)" ::: "memory");
        if (s < NSTRIPE - 1 && f >= 1 && lane == 0)
            st_flag(fmy, FLAGTAG + (unsigned)f);
        // 3) flush chunk f: 4 rows x 256 cols; lane stores its 4 cols.
        if (f >= 0) {
            #pragma unroll
            for (int rr = 0; rr < CH; ++rr) {
                const int rw = (f << 2) + rr;
                const float4 v = *(const float4*)
                    &lds_o[(rw & 127) * LSTR + 4 * lane];
                float* orow = ob + (size_t)(rw + 1) * OCOLS + s * SW + 1
                            + 4 * lane;
                orow[0] = v.x; orow[1] = v.y; orow[2] = v.z; orow[3] = v.w;
            }
        }
        // 4) rotate edge regs; load chunk m+3 (need flag m+4, polled tt==1)
        evcur = evnxt; evnxt = lres;
        const int c = m + 3;
        if (s > 0 && c < NCHUNK) {
            const unsigned need = (unsigned)(m + 4);
            if (!((fpoll >> 24) == 0x5Au && (fpoll & 0x00FFFFFFu) >= need))
                wait_flag(fup, need);
            lres = -1e30f;
            if (lane < CH)
                lres = (use_stage ? ld_edge(&eup[(size_t)c * 4 + lane])
                                  : ld_edge(&ob[(size_t)((c << 2) + 1 + lane) * OCOLS + s * SW]))
                       * LOG2E;
        }
    };

    // ---- prologue: m=0..15 (some lanes r<0; full gating) ----
    for (int m = 0; m < 16; ++m) {
        #pragma unroll
        for (int tt = 0; tt < 4; ++tt) stepc(m, tt, true, false);
        boundary(m);
    }
    // ---- middle: m=16..127 (t in [64,511]: every lane 0<=r<NA) ----
    for (int m = 16; m < 128; ++m) {
        #pragma unroll
        for (int tt = 0; tt < 4; ++tt) stepc(m, tt, false, false);
        boundary(m);
    }
    // ---- epilogue: m=128..142 (store guard only) ----
    for (int m = 128; m < 143; ++m) {
        #pragma unroll
        for (int tt = 0; tt < 4; ++tt) stepc(m, tt, false, true);
        boundary(m);
    }
    // tail steps t = 572..574 (lane 63 finishes row 511 at t=574)
    #pragma unroll
    for (int tt = 0; tt < 3; ++tt) stepc(143, tt, false, true);

    // ---- final: chunk 127 ----
    {
        const int f = NCHUNK - 1;
        if (s < NSTRIPE - 1 && lane < CH) {
            const int rw = (f << 2) + lane;
            const float evl = lds_o[(rw & 127) * LSTR + (SW - 1)];
            if (use_stage) st_edge(&emy[(size_t)f * 4 + lane], evl);
            else st_edge(ob + (size_t)(rw + 1) * OCOLS + (s + 1) * SW, evl);
        }
        // publish(126) from boundary m=142 is 7 vmem ops back -> drained
        asm volatile("s_waitcnt vmcnt(1)" ::: "memory");
        if (s < NSTRIPE - 1 && lane == 0)
            st_flag(fmy, FLAGTAG + (unsigned)f);          // chunks <= 126
        #pragma unroll
        for (int rr = 0; rr < CH; ++rr) {
            const int rw = (f << 2) + rr;
            const float4 v = *(const float4*)
                &lds_o[(rw & 127) * LSTR + 4 * lane];
            float* orow = ob + (size_t)(rw + 1) * OCOLS + s * SW + 1
                        + 4 * lane;
            orow[0] = v.x; orow[1] = v.y; orow[2] = v.z; orow[3] = v.w;
        }
        asm volatile("s_waitcnt vmcnt(0)" ::: "memory");
        if (s < NSTRIPE - 1 && lane == 0)
            st_flag(fmy, FLAGTAG + (unsigned)NCHUNK);     // all 128 chunks
    }
}

extern "C" void kernel_launch(void* const* d_in, const int* in_sizes, int n_in,
                              void* d_out, int out_size, void* d_ws, size_t ws_size,
                              hipStream_t stream) {
    const float*  W     = (const float*)d_in[0];
    float*        out   = (float*)d_out;
    unsigned int* flags = (unsigned int*)d_ws;
    (void)in_sizes; (void)n_in; (void)out_size;
    const int use_stage = (ws_size >= WS_NEEDED) ? 1 : 0;
    hipLaunchKernelGGL(dtw_pipe, dim3(NBID), dim3(64),
                       128 * LSTR * sizeof(float), stream,
                       W, out, flags, use_stage);
}